// Round 12
// baseline (211.576 us; speedup 1.0000x reference)
//
#include <hip/hip_runtime.h>

// ---------------- types / helpers ----------------
typedef unsigned short u16;
typedef float f32x4 __attribute__((ext_vector_type(4)));
typedef short bf16x8 __attribute__((ext_vector_type(8)));

__device__ __forceinline__ u16 f2bf(float f) {
    unsigned u = __float_as_uint(f);
    u = (u + 0x7FFFu + ((u >> 16) & 1u)) >> 16;
    return (u16)u;
}

#define LOG2E 1.4426950408889634f

#if __has_builtin(__builtin_amdgcn_exp2f)
__device__ __forceinline__ float exp2_fast(float x) { return __builtin_amdgcn_exp2f(x); }
#else
__device__ __forceinline__ float exp2_fast(float x) { return __expf(x * 0.6931471805599453f); }
#endif

__device__ __forceinline__ unsigned pack2bf(float a, float b) {
    unsigned ua = __float_as_uint(a) + 0x8000u;
    unsigned ub = __float_as_uint(b) + 0x8000u;
#if __has_builtin(__builtin_amdgcn_perm)
    return __builtin_amdgcn_perm(ub, ua, 0x07060302u);
#else
    return ((ua >> 16) & 0xFFFFu) | (ub & 0xFFFF0000u);
#endif
}

#if __has_builtin(__builtin_amdgcn_cvt_pk_bf16_f32)
typedef __bf16 bf2_t __attribute__((ext_vector_type(2)));
__device__ __forceinline__ unsigned cvtpk(float a, float b) {
    bf2_t r = __builtin_amdgcn_cvt_pk_bf16_f32(a, b);
    return __builtin_bit_cast(unsigned, r);
}
#else
__device__ __forceinline__ unsigned cvtpk(float a, float b) { return pack2bf(a, b); }
#endif

__device__ __forceinline__ bf16x8 bc8(uint4 u) { return __builtin_bit_cast(bf16x8, u); }

// async 16B/lane global->LDS DMA; lds dst = wave-uniform base + lane*16.
#if __has_builtin(__builtin_amdgcn_global_load_lds)
typedef const __attribute__((address_space(1))) void* as1cv;
typedef __attribute__((address_space(3))) void* as3v;
__device__ __forceinline__ void dma16(const void* g, void* lds_base, int lane) {
    __builtin_amdgcn_global_load_lds((as1cv)g, (as3v)lds_base, 16, 0, 0);
}
#else
__device__ __forceinline__ void dma16(const void* g, void* lds_base, int lane) {
    *(uint4*)((char*)lds_base + lane * 16) = *(const uint4*)g;
}
#endif

// Problem constants. DEDUP: only 3136 unique keys; multiplicity {1,2,4} folded
// into V (pre-scaled) + counts row. All layouts are wave-linear fragment tiles.
// V is PAIR-INTERLEAVED: per (bh, chunk ch, wave w) a 2KB block
// [vh=d-half][reader-lane][16B = {tileA keys 8B, tileB keys 8B}] so attn's PV
// B-fragment is one linear 16B/lane read (now a global dwordx4 into VGPRs).
#define BB 2
#define HH 56
#define SQ 3136
#define CROWN 3584

// workspace offsets (u16 units)
#define WS_Q    0         // 392 tiles * 4096
#define WS_K    1605632   // 2 b * 200 tiles * 4096 (196 real + 4 pad)
#define WS_V    3244032   // 16 bh * 25 ch * 4 pair * 1024
#define WS_WT   4882432   // 3*65536 fragment-packed weights
#define WS_CB   5079040   // 3584 u16 bf16 counts
#define WS_XB   5082624   // 392 tiles * 4096 bf16 x

// ---------------- kernel 0: fused prep (weights + x + crow + pad zeros) ------------
__global__ __launch_bounds__(256) void prep_kernel(const float* __restrict__ x,
                                                   const float* __restrict__ Wq,
                                                   const float* __restrict__ Wk,
                                                   const float* __restrict__ Wv,
                                                   u16* __restrict__ wtf,
                                                   u16* __restrict__ kbf,
                                                   u16* __restrict__ vbf,
                                                   u16* __restrict__ crow,
                                                   u16* __restrict__ xbf) {
    __shared__ __align__(16) char SM[17408];
    int tid = threadIdx.x;
    int bid = blockIdx.x;

    if (bid < 48) {
        u16 (*T)[68] = (u16(*)[68])SM;
        int mode = bid >> 4, rem = bid & 15;
        int kx = (rem >> 2) * 64, dx = (rem & 3) * 64;
        const float* W = (mode == 0) ? Wq : ((mode == 1) ? Wk : Wv);
        float sc = (mode == 0) ? LOG2E : 1.0f;
        int r16 = tid >> 4, c4 = (tid & 15) * 4;
#pragma unroll
        for (int p = 0; p < 4; ++p) {
            int kr = p * 16 + r16;
            float4 f = *(const float4*)&W[(size_t)(kx + kr) * 256 + dx + c4];
            T[kr][c4 + 0] = f2bf(f.x * sc);
            T[kr][c4 + 1] = f2bf(f.y * sc);
            T[kr][c4 + 2] = f2bf(f.z * sc);
            T[kr][c4 + 3] = f2bf(f.w * sc);
        }
        __syncthreads();
        int l16 = tid & 15, nt_loc = (tid >> 4) & 3, quad = (tid >> 6) & 3;
#pragma unroll
        for (int s_loc = 0; s_loc < 2; ++s_loc) {
            int k0 = s_loc * 32 + quad * 8;
            int d_loc = nt_loc * 16 + l16;
            u16 tmp[8];
#pragma unroll
            for (int j = 0; j < 8; ++j) tmp[j] = T[k0 + j][d_loc];
            int d = dx + d_loc;
            int nz = d >> 7, ntg = (d >> 4) & 7;
            int s = (kx >> 5) + s_loc;
            int f = (nz * 8 + s) * 8 + ntg;
            int L = quad * 16 + l16;
            *(uint4*)&wtf[(size_t)mode * 65536 + (size_t)f * 512 + (size_t)L * 8] = *(uint4*)tmp;
        }
        uint4 z4 = (uint4){0, 0, 0, 0};
        if (mode == 0 && kx == 0 && dx == 0) {
            // zero K pad tiles 196..199 per b
            for (int i = tid; i < 4096; i += 256) {
                int bb = i >> 11, rem2 = i & 2047;
                int t = 196 + (rem2 >> 9), off = (rem2 & 511) * 8;
                *(uint4*)&kbf[(((size_t)(bb * 200 + t)) << 12) + off] = z4;
            }
        }
        if (mode == 1 && kx == 0 && dx == 0) {
            for (int i = tid; i < CROWN; i += 256) {
                u16 v = 0;
                if (i < SQ) {
                    int rr = i / 56, cc = i - rr * 56;
                    int mr = (((rr >= 1) && (rr <= 3)) || ((rr >= 52) && (rr <= 54))) ? 2 : 1;
                    int mc = (((cc >= 1) && (cc <= 3)) || ((cc >= 52) && (cc <= 54))) ? 2 : 1;
                    int prod = mr * mc;
                    v = (prod == 1) ? (u16)0x3F80 : ((prod == 2) ? (u16)0x4000 : (u16)0x4080);
                }
                crow[i] = v;
            }
        }
        if (mode == 2 && kx == 0 && dx == 0) {
            // zero pair-layout tile-B halves of chunk 24 (pad keys 3136..3199)
            for (int i = tid; i < 8192; i += 256) {
                int bh = i >> 9, rem2 = i & 511;
                int wp = rem2 >> 7, rem3 = rem2 & 127;
                int vh = rem3 >> 6, ln = rem3 & 63;
                size_t off = (size_t)bh * 102400 + (size_t)(96 + wp) * 1024
                           + (size_t)vh * 512 + (size_t)ln * 8 + 4;
                *(uint2*)&vbf[off] = (uint2){0, 0};
            }
        }
    } else {
        float (*T)[256] = (float(*)[256])SM;
        int tile = bid - 48;
        int r = tid >> 4, c0 = (tid & 15) * 16;
        const float* src = x + ((size_t)tile * 16 + r) * 256 + c0;
#pragma unroll
        for (int k = 0; k < 4; ++k)
            *(float4*)&T[r][c0 + k * 4] = *(const float4*)&src[k * 4];
        __syncthreads();
#pragma unroll
        for (int e = 0; e < 2; ++e) {
            int g = tid + e * 256;                  // granule 0..511
            int s = g >> 6, L = g & 63;
            const float* row = &T[L & 15][s * 32 + (L >> 4) * 8];
            uint4 pk = (uint4){pack2bf(row[0], row[1]), pack2bf(row[2], row[3]),
                               pack2bf(row[4], row[5]), pack2bf(row[6], row[7])};
            *(uint4*)&xbf[(size_t)tile * 4096 + (size_t)g * 8] = pk;
        }
    }
}

// ---------------- kernel 1: projections (unchanged from round 11) ------------------
__global__ __launch_bounds__(256, 4) void proj_kernel(const u16* __restrict__ xbf,
                                                      const u16* __restrict__ wtf,
                                                      const float* __restrict__ bq,
                                                      const float* __restrict__ bk,
                                                      const float* __restrict__ bv,
                                                      u16* __restrict__ qbf,
                                                      u16* __restrict__ kbf,
                                                      u16* __restrict__ vbf) {
    int mode = blockIdx.y, nz = blockIdx.z;
    int mbase = blockIdx.x * 64;
    int tid = threadIdx.x;
    int wave = tid >> 6, lane = tid & 63, quad = (tid >> 4) & 3, l16 = tid & 15;
    const float* bias = (mode == 0) ? bq : ((mode == 1) ? bk : bv);
    float wsc = (mode == 0) ? LOG2E : 1.0f;
    const u16* wf = wtf + (size_t)mode * 65536 + (size_t)nz * 32768 + (size_t)lane * 8;
    const u16* xt = xbf + (((size_t)(mbase >> 4) + wave) << 12);   // tile base (*4096)

    f32x4 acc[8];
#pragma unroll
    for (int i = 0; i < 8; i++) acc[i] = (f32x4){0.f, 0.f, 0.f, 0.f};

#pragma unroll
    for (int s = 0; s < 8; ++s) {
        bf16x8 af = *(const bf16x8*)&xt[(s << 9) + lane * 8];
        if (mode == 2) {
#pragma unroll
            for (int nt = 0; nt < 8; nt++) {
                bf16x8 bfrag = *(const bf16x8*)&wf[(s * 8 + nt) * 512];
                acc[nt] = __builtin_amdgcn_mfma_f32_16x16x32_bf16(af, bfrag, acc[nt], 0, 0, 0);
            }
        } else {
#pragma unroll
            for (int nt = 0; nt < 8; nt++) {
                bf16x8 bfrag = *(const bf16x8*)&wf[(s * 8 + nt) * 512];
                acc[nt] = __builtin_amdgcn_mfma_f32_16x16x32_bf16(bfrag, af, acc[nt], 0, 0, 0);
            }
        }
    }

    if (mode == 2) {
        int b_ = (mbase >= SQ) ? 1 : 0;
        int kp0 = mbase - b_ * SQ + wave * 16 + quad * 4;
        int rg = (mbase - b_ * SQ + wave * 16) >> 4;
        int ch = rg >> 3, wp = rg & 3, which = (rg >> 2) & 1;
        float mult[4];
#pragma unroll
        for (int p = 0; p < 4; ++p) {
            int kp = kp0 + p;
            int rr = kp / 56, cc = kp - rr * 56;
            float mr = (((rr >= 1) && (rr <= 3)) || ((rr >= 52) && (rr <= 54))) ? 2.f : 1.f;
            float mc = (((cc >= 1) && (cc <= 3)) || ((cc >= 52) && (cc <= 54))) ? 2.f : 1.f;
            mult[p] = mr * mc;
        }
#pragma unroll
        for (int nt = 0; nt < 8; nt++) {
            int c = nz * 128 + nt * 16 + l16;
            float bvv = bias[c];
            int h_idx = nz * 4 + (nt >> 1);
            int bh2 = b_ * 8 + h_idx;
            float va0 = (acc[nt][0] + bvv) * mult[0];
            float va1 = (acc[nt][1] + bvv) * mult[1];
            float va2 = (acc[nt][2] + bvv) * mult[2];
            float va3 = (acc[nt][3] + bvv) * mult[3];
            uint2 pk = (uint2){pack2bf(va0, va1), pack2bf(va2, va3)};
            size_t off = (size_t)bh2 * 102400 + (size_t)(ch * 4 + wp) * 1024
                       + (size_t)(nt & 1) * 512 + (size_t)(quad * 16 + l16) * 8 + which * 4;
            *(uint2*)&vbf[off] = pk;
        }
    } else {
        u16* outp = (mode == 0) ? qbf : kbf;
        int t = (mbase >> 4) + wave;
        int tt = (mode == 0) ? t : (t + (t >= 196 ? 4 : 0));
#pragma unroll
        for (int nt = 0; nt < 8; nt++) {
            int c0 = nz * 128 + nt * 16 + quad * 4;
            float4 b4 = *(const float4*)&bias[c0];
            float v0 = acc[nt][0] + b4.x * wsc;
            float v1 = acc[nt][1] + b4.y * wsc;
            float v2 = acc[nt][2] + b4.z * wsc;
            float v3 = acc[nt][3] + b4.w * wsc;
            int s_idx = nz * 4 + (nt >> 1);
            int Lrow = ((nt & 1) * 2 + (quad >> 1)) * 16 + l16;
            uint2 pk = (uint2){pack2bf(v0, v1), pack2bf(v2, v3)};
            *(uint2*)&outp[(((size_t)(tt * 8 + s_idx)) << 9) + Lrow * 8 + (quad & 1) * 4] = pk;
        }
    }
}

// ---------------- kernel 2: flash attention (half-query blocks, 2x wave density) ---
// grid (16 bh, 98 qsub): 1568 blocks x 4 waves of 32 QUERIES each = 6272 waves
// (~6.1/SIMD vs 3.06 before). LDS 22.5KB + launch_bounds(256,7) -> 7 blocks/CU
// = 1792 slots >= 1568: single generation. K double-buffered in LDS (wave-
// private, barrier-free); V staged to REGISTERS (T14, depth-1 ping-pong via
// 2-unroll); counts rounds 0..23 in LDS, round-24 counts preloaded (tile-B
// half is pad => 0). 4 VMEM ops/round, counted vmcnt(4). setprio on MFMA.
__global__ __launch_bounds__(256, 7) void attn_kernel(const u16* __restrict__ qb,
                                                      const u16* __restrict__ kb,
                                                      const u16* __restrict__ vtb,
                                                      const u16* __restrict__ crow,
                                                      const float* __restrict__ x,
                                                      const float* __restrict__ gammap,
                                                      float* __restrict__ out) {
    __shared__ __align__(16) u16 S[11264];   // K bufs 2*4096; cnt rounds 0..23 @8192

    int tid = threadIdx.x;
    int w = tid >> 6, lane = tid & 63, quad = lane >> 4, l16 = lane & 15;
    int bh = blockIdx.x;
    int b = bh >> 3, h = bh & 7;
    int qy = blockIdx.y;
    int qsub = qy * 32;

    int qtile = b * 196 + qy * 2;
    bf16x8 qf[2];
#pragma unroll
    for (int i = 0; i < 2; ++i)
        qf[i] = *(const bf16x8*)&qb[(((size_t)(qtile + i) * 8 + h) << 9) + lane * 8];

    const u16* kg = kb + ((size_t)(b * 200) << 12);     // b's K tile base
    const u16* vg = vtb + (size_t)bh * 102400;          // (b,h) V pair-block base

    f32x4 o[2][2], lv[2];
#pragma unroll
    for (int i = 0; i < 2; ++i) {
        o[i][0] = (f32x4){0.f, 0.f, 0.f, 0.f};
        o[i][1] = (f32x4){0.f, 0.f, 0.f, 0.f};
        lv[i]   = (f32x4){0.f, 0.f, 0.f, 0.f};
    }

    int tA = w, tB = w + 4;
    int kOffA = tA * 512 + lane * 8;
    int kOffB = tB * 512 + lane * 8;
    int cOffA = tA * 16 + quad * 4;
    int cOffB = tB * 16 + quad * 4;

    // round-24 counts: tile-A from global (L2-hot), tile-B half is pad => 0
    uint2 ca24 = *(const uint2*)&crow[3072 + cOffA];

    auto stageK = [&](int r, int buf) {
        u16* base = &S[buf * 4096];
        dma16(kg + (((size_t)((r * 8 + tA) * 8 + h)) << 9) + lane * 8, base + tA * 512, lane);
        dma16(kg + (((size_t)((r * 8 + tB) * 8 + h)) << 9) + lane * 8, base + tB * 512, lane);
    };
    auto loadV = [&](int r, uint4& v0, uint4& v1) {
        const u16* vsrc = vg + (size_t)r * 4096 + w * 1024 + lane * 8;
        v0 = *(const uint4*)&vsrc[0];
        v1 = *(const uint4*)&vsrc[512];
    };
    auto cfLDS = [&](int r) -> bf16x8 {
        const u16* cnt = &S[8192 + r * 128];
        uint2 ca = *(const uint2*)&cnt[cOffA];
        uint2 cc = *(const uint2*)&cnt[cOffB];
        return bc8((uint4){ca.x, ca.y, cc.x, cc.y});
    };

    auto body = [&](int bR, uint4 v0, uint4 v1, bf16x8 cf) {
        const u16* Kl = &S[bR * 4096];
        f32x4 z = (f32x4){0.f, 0.f, 0.f, 0.f};
        unsigned paw[2][4];
        {
            bf16x8 kfA = *(const bf16x8*)&Kl[kOffA];
            f32x4 eA[2];
            __builtin_amdgcn_s_setprio(1);
#pragma unroll
            for (int i = 0; i < 2; ++i)
                eA[i] = __builtin_amdgcn_mfma_f32_16x16x32_bf16(kfA, qf[i], z, 0, 0, 0);
            __builtin_amdgcn_s_setprio(0);
#pragma unroll
            for (int i = 0; i < 2; ++i) {
                paw[i][0] = cvtpk(exp2_fast(eA[i][0]), exp2_fast(eA[i][1]));
                paw[i][1] = cvtpk(exp2_fast(eA[i][2]), exp2_fast(eA[i][3]));
            }
        }
        {
            bf16x8 kfB = *(const bf16x8*)&Kl[kOffB];
            f32x4 eB[2];
            __builtin_amdgcn_s_setprio(1);
#pragma unroll
            for (int i = 0; i < 2; ++i)
                eB[i] = __builtin_amdgcn_mfma_f32_16x16x32_bf16(kfB, qf[i], z, 0, 0, 0);
            __builtin_amdgcn_s_setprio(0);
#pragma unroll
            for (int i = 0; i < 2; ++i) {
                paw[i][2] = cvtpk(exp2_fast(eB[i][0]), exp2_fast(eB[i][1]));
                paw[i][3] = cvtpk(exp2_fast(eB[i][2]), exp2_fast(eB[i][3]));
            }
        }
        bf16x8 V0 = bc8(v0), V1 = bc8(v1);
        __builtin_amdgcn_s_setprio(1);
#pragma unroll
        for (int i = 0; i < 2; ++i) {
            bf16x8 pa = bc8((uint4){paw[i][0], paw[i][1], paw[i][2], paw[i][3]});
            o[i][0] = __builtin_amdgcn_mfma_f32_16x16x32_bf16(pa, V0, o[i][0], 0, 0, 0);
            o[i][1] = __builtin_amdgcn_mfma_f32_16x16x32_bf16(pa, V1, o[i][1], 0, 0, 0);
            lv[i]   = __builtin_amdgcn_mfma_f32_16x16x32_bf16(pa, cf, lv[i], 0, 0, 0);
        }
        __builtin_amdgcn_s_setprio(0);
    };

    // prologue: cnt chunks 0..5 (rounds 0..23) + K(0) + V(0); barrier drains all
    dma16(crow + w * 512 + lane * 8, (char*)&S[8192] + w * 1024, lane);
    if (w < 2)
        dma16(crow + (w + 4) * 512 + lane * 8, (char*)&S[8192] + (w + 4) * 1024, lane);
    stageK(0, 0);
    uint4 va0, va1, vb0, vb1;
    loadV(0, va0, va1);
    __syncthreads();          // compiler drains vmcnt(0): cnt + K(0) + V(0) + ca24 ready

    for (int j = 0; j < 12; ++j) {
        int r = 2 * j;
        // even round r: consume buf0 + Va; prefetch r+1 into buf1 + Vb
        stageK(r + 1, 1);
        loadV(r + 1, vb0, vb1);
        asm volatile("s_waitcnt vmcnt(4)" ::: "memory");
        body(0, va0, va1, cfLDS(r));
        // odd round r+1: consume buf1 + Vb; prefetch r+2 into buf0 + Va
        stageK(r + 2, 0);
        loadV(r + 2, va0, va1);
        asm volatile("s_waitcnt vmcnt(4)" ::: "memory");
        body(1, vb0, vb1, cfLDS(r + 1));
    }
    // round 24 (staged during j=11 odd iter into buf0/Va)
    asm volatile("s_waitcnt vmcnt(0)" ::: "memory");
    body(0, va0, va1, bc8((uint4){ca24.x, ca24.y, 0u, 0u}));

    __syncthreads();                 // all waves done; LDS reusable

    // ---- two-stage merge of 4 key-roles via LDS (24 floats/lane payload) ----
    float* mg = (float*)&S[0];
    {
        int slot = ((w & 1) * 64 + lane) * 24;
        if (w >= 2) {
            *(f32x4*)&mg[slot + 0]  = o[0][0];
            *(f32x4*)&mg[slot + 4]  = o[0][1];
            *(f32x4*)&mg[slot + 8]  = o[1][0];
            *(f32x4*)&mg[slot + 12] = o[1][1];
            *(f32x4*)&mg[slot + 16] = lv[0];
            *(f32x4*)&mg[slot + 20] = lv[1];
        }
        __syncthreads();
        if (w < 2) {
            o[0][0] += *(const f32x4*)&mg[slot + 0];
            o[0][1] += *(const f32x4*)&mg[slot + 4];
            o[1][0] += *(const f32x4*)&mg[slot + 8];
            o[1][1] += *(const f32x4*)&mg[slot + 12];
            lv[0]   += *(const f32x4*)&mg[slot + 16];
            lv[1]   += *(const f32x4*)&mg[slot + 20];
        }
        __syncthreads();
    }
    {
        int slot = lane * 24;
        if (w == 1) {
            *(f32x4*)&mg[slot + 0]  = o[0][0];
            *(f32x4*)&mg[slot + 4]  = o[0][1];
            *(f32x4*)&mg[slot + 8]  = o[1][0];
            *(f32x4*)&mg[slot + 12] = o[1][1];
            *(f32x4*)&mg[slot + 16] = lv[0];
            *(f32x4*)&mg[slot + 20] = lv[1];
        }
        __syncthreads();
        if (w == 0) {
            float gam = gammap[0];
            o[0][0] += *(const f32x4*)&mg[slot + 0];
            o[0][1] += *(const f32x4*)&mg[slot + 4];
            o[1][0] += *(const f32x4*)&mg[slot + 8];
            o[1][1] += *(const f32x4*)&mg[slot + 12];
            lv[0]   += *(const f32x4*)&mg[slot + 16];
            lv[1]   += *(const f32x4*)&mg[slot + 20];
#pragma unroll
            for (int i = 0; i < 2; ++i) {
#pragma unroll
                for (int r2 = 0; r2 < 4; ++r2) {
                    float scl = gam / lv[i][r2];
                    int q = qsub + i * 16 + quad * 4 + r2;
                    size_t base = ((size_t)(b * SQ + q) << 8) + h * 32 + l16;
                    out[base]      = o[i][0][r2] * scl + x[base];
                    out[base + 16] = o[i][1][r2] * scl + x[base + 16];
                }
            }
        }
    }
}

// ---------------- launcher ----------------
extern "C" void kernel_launch(void* const* d_in, const int* in_sizes, int n_in,
                              void* d_out, int out_size, void* d_ws, size_t ws_size,
                              hipStream_t stream) {
    const float* x     = (const float*)d_in[0];
    const float* Wq    = (const float*)d_in[1];
    const float* bq    = (const float*)d_in[2];
    const float* Wk    = (const float*)d_in[3];
    const float* bk    = (const float*)d_in[4];
    const float* Wv    = (const float*)d_in[5];
    const float* bv    = (const float*)d_in[6];
    const float* gamma = (const float*)d_in[7];
    float* out = (float*)d_out;

    u16* ws   = (u16*)d_ws;
    u16* qbf  = ws + WS_Q;
    u16* kbf  = ws + WS_K;
    u16* vbf  = ws + WS_V;
    u16* wtf  = ws + WS_WT;
    u16* crow = ws + WS_CB;
    u16* xbf  = ws + WS_XB;

    prep_kernel<<<440, 256, 0, stream>>>(x, Wq, Wk, Wv, wtf, kbf, vbf, crow, xbf);
    proj_kernel<<<dim3(98, 3, 2), 256, 0, stream>>>(xbf, wtf, bq, bk, bv, qbf, kbf, vbf);
    attn_kernel<<<dim3(16, 98), 256, 0, stream>>>(qbf, kbf, vbf, crow, x, gamma, out);
}

// Round 13
// 185.167 us; speedup vs baseline: 1.1426x; 1.1426x over previous
//
#include <hip/hip_runtime.h>

// ---------------- types / helpers ----------------
typedef unsigned short u16;
typedef float f32x4 __attribute__((ext_vector_type(4)));
typedef short bf16x8 __attribute__((ext_vector_type(8)));

__device__ __forceinline__ u16 f2bf(float f) {
    unsigned u = __float_as_uint(f);
    u = (u + 0x7FFFu + ((u >> 16) & 1u)) >> 16;
    return (u16)u;
}

#define LOG2E 1.4426950408889634f

#if __has_builtin(__builtin_amdgcn_exp2f)
__device__ __forceinline__ float exp2_fast(float x) { return __builtin_amdgcn_exp2f(x); }
#else
__device__ __forceinline__ float exp2_fast(float x) { return __expf(x * 0.6931471805599453f); }
#endif

__device__ __forceinline__ unsigned pack2bf(float a, float b) {
    unsigned ua = __float_as_uint(a) + 0x8000u;
    unsigned ub = __float_as_uint(b) + 0x8000u;
#if __has_builtin(__builtin_amdgcn_perm)
    return __builtin_amdgcn_perm(ub, ua, 0x07060302u);
#else
    return ((ua >> 16) & 0xFFFFu) | (ub & 0xFFFF0000u);
#endif
}

#if __has_builtin(__builtin_amdgcn_cvt_pk_bf16_f32)
typedef __bf16 bf2_t __attribute__((ext_vector_type(2)));
__device__ __forceinline__ unsigned cvtpk(float a, float b) {
    bf2_t r = __builtin_amdgcn_cvt_pk_bf16_f32(a, b);
    return __builtin_bit_cast(unsigned, r);
}
#else
__device__ __forceinline__ unsigned cvtpk(float a, float b) { return pack2bf(a, b); }
#endif

__device__ __forceinline__ bf16x8 bc8(uint4 u) { return __builtin_bit_cast(bf16x8, u); }

// async 16B/lane global->LDS DMA; lds dst = wave-uniform base + lane*16.
#if __has_builtin(__builtin_amdgcn_global_load_lds)
typedef const __attribute__((address_space(1))) void* as1cv;
typedef __attribute__((address_space(3))) void* as3v;
__device__ __forceinline__ void dma16(const void* g, void* lds_base, int lane) {
    __builtin_amdgcn_global_load_lds((as1cv)g, (as3v)lds_base, 16, 0, 0);
}
#else
__device__ __forceinline__ void dma16(const void* g, void* lds_base, int lane) {
    *(uint4*)((char*)lds_base + lane * 16) = *(const uint4*)g;
}
#endif

// Problem constants. DEDUP: only 3136 unique keys; multiplicity {1,2,4} folded
// into V (pre-scaled) + counts row. All layouts are wave-linear fragment tiles.
// V is PAIR-INTERLEAVED: per (bh, chunk ch, wave w) a 2KB block
// [vh=d-half][reader-lane][16B = {tileA keys 8B, tileB keys 8B}] so attn's PV
// B-fragment is one linear 16B/lane global dwordx4 into VGPRs.
#define BB 2
#define HH 56
#define SQ 3136
#define CROWN 3584

// workspace offsets (u16 units)
#define WS_Q    0         // 392 tiles * 4096
#define WS_K    1605632   // 2 b * 200 tiles * 4096 (196 real + 4 pad)
#define WS_V    3244032   // 16 bh * 25 ch * 4 pair * 1024
#define WS_WT   4882432   // 3*65536 fragment-packed weights
#define WS_CB   5079040   // 3584 u16 bf16 counts
#define WS_XB   5082624   // 392 tiles * 4096 bf16 x

// ---------------- kernel 0: fused prep (weights + x + crow + pad zeros) ------------
__global__ __launch_bounds__(256) void prep_kernel(const float* __restrict__ x,
                                                   const float* __restrict__ Wq,
                                                   const float* __restrict__ Wk,
                                                   const float* __restrict__ Wv,
                                                   u16* __restrict__ wtf,
                                                   u16* __restrict__ kbf,
                                                   u16* __restrict__ vbf,
                                                   u16* __restrict__ crow,
                                                   u16* __restrict__ xbf) {
    __shared__ __align__(16) char SM[17408];
    int tid = threadIdx.x;
    int bid = blockIdx.x;

    if (bid < 48) {
        u16 (*T)[68] = (u16(*)[68])SM;
        int mode = bid >> 4, rem = bid & 15;
        int kx = (rem >> 2) * 64, dx = (rem & 3) * 64;
        const float* W = (mode == 0) ? Wq : ((mode == 1) ? Wk : Wv);
        float sc = (mode == 0) ? LOG2E : 1.0f;
        int r16 = tid >> 4, c4 = (tid & 15) * 4;
#pragma unroll
        for (int p = 0; p < 4; ++p) {
            int kr = p * 16 + r16;
            float4 f = *(const float4*)&W[(size_t)(kx + kr) * 256 + dx + c4];
            T[kr][c4 + 0] = f2bf(f.x * sc);
            T[kr][c4 + 1] = f2bf(f.y * sc);
            T[kr][c4 + 2] = f2bf(f.z * sc);
            T[kr][c4 + 3] = f2bf(f.w * sc);
        }
        __syncthreads();
        int l16 = tid & 15, nt_loc = (tid >> 4) & 3, quad = (tid >> 6) & 3;
#pragma unroll
        for (int s_loc = 0; s_loc < 2; ++s_loc) {
            int k0 = s_loc * 32 + quad * 8;
            int d_loc = nt_loc * 16 + l16;
            u16 tmp[8];
#pragma unroll
            for (int j = 0; j < 8; ++j) tmp[j] = T[k0 + j][d_loc];
            int d = dx + d_loc;
            int nz = d >> 7, ntg = (d >> 4) & 7;
            int s = (kx >> 5) + s_loc;
            int f = (nz * 8 + s) * 8 + ntg;
            int L = quad * 16 + l16;
            *(uint4*)&wtf[(size_t)mode * 65536 + (size_t)f * 512 + (size_t)L * 8] = *(uint4*)tmp;
        }
        uint4 z4 = (uint4){0, 0, 0, 0};
        if (mode == 0 && kx == 0 && dx == 0) {
            // zero K pad tiles 196..199 per b
            for (int i = tid; i < 4096; i += 256) {
                int bb = i >> 11, rem2 = i & 2047;
                int t = 196 + (rem2 >> 9), off = (rem2 & 511) * 8;
                *(uint4*)&kbf[(((size_t)(bb * 200 + t)) << 12) + off] = z4;
            }
        }
        if (mode == 1 && kx == 0 && dx == 0) {
            for (int i = tid; i < CROWN; i += 256) {
                u16 v = 0;
                if (i < SQ) {
                    int rr = i / 56, cc = i - rr * 56;
                    int mr = (((rr >= 1) && (rr <= 3)) || ((rr >= 52) && (rr <= 54))) ? 2 : 1;
                    int mc = (((cc >= 1) && (cc <= 3)) || ((cc >= 52) && (cc <= 54))) ? 2 : 1;
                    int prod = mr * mc;
                    v = (prod == 1) ? (u16)0x3F80 : ((prod == 2) ? (u16)0x4000 : (u16)0x4080);
                }
                crow[i] = v;
            }
        }
        if (mode == 2 && kx == 0 && dx == 0) {
            // zero pair-layout tile-B halves of chunk 24 (pad keys 3136..3199)
            for (int i = tid; i < 8192; i += 256) {
                int bh = i >> 9, rem2 = i & 511;
                int wp = rem2 >> 7, rem3 = rem2 & 127;
                int vh = rem3 >> 6, ln = rem3 & 63;
                size_t off = (size_t)bh * 102400 + (size_t)(96 + wp) * 1024
                           + (size_t)vh * 512 + (size_t)ln * 8 + 4;
                *(uint2*)&vbf[off] = (uint2){0, 0};
            }
        }
    } else {
        float (*T)[256] = (float(*)[256])SM;
        int tile = bid - 48;
        int r = tid >> 4, c0 = (tid & 15) * 16;
        const float* src = x + ((size_t)tile * 16 + r) * 256 + c0;
#pragma unroll
        for (int k = 0; k < 4; ++k)
            *(float4*)&T[r][c0 + k * 4] = *(const float4*)&src[k * 4];
        __syncthreads();
#pragma unroll
        for (int e = 0; e < 2; ++e) {
            int g = tid + e * 256;                  // granule 0..511
            int s = g >> 6, L = g & 63;
            const float* row = &T[L & 15][s * 32 + (L >> 4) * 8];
            uint4 pk = (uint4){pack2bf(row[0], row[1]), pack2bf(row[2], row[3]),
                               pack2bf(row[4], row[5]), pack2bf(row[6], row[7])};
            *(uint4*)&xbf[(size_t)tile * 4096 + (size_t)g * 8] = pk;
        }
    }
}

// ---------------- kernel 1: projections (unchanged from round 11) ------------------
__global__ __launch_bounds__(256, 4) void proj_kernel(const u16* __restrict__ xbf,
                                                      const u16* __restrict__ wtf,
                                                      const float* __restrict__ bq,
                                                      const float* __restrict__ bk,
                                                      const float* __restrict__ bv,
                                                      u16* __restrict__ qbf,
                                                      u16* __restrict__ kbf,
                                                      u16* __restrict__ vbf) {
    int mode = blockIdx.y, nz = blockIdx.z;
    int mbase = blockIdx.x * 64;
    int tid = threadIdx.x;
    int wave = tid >> 6, lane = tid & 63, quad = (tid >> 4) & 3, l16 = tid & 15;
    const float* bias = (mode == 0) ? bq : ((mode == 1) ? bk : bv);
    float wsc = (mode == 0) ? LOG2E : 1.0f;
    const u16* wf = wtf + (size_t)mode * 65536 + (size_t)nz * 32768 + (size_t)lane * 8;
    const u16* xt = xbf + (((size_t)(mbase >> 4) + wave) << 12);   // tile base (*4096)

    f32x4 acc[8];
#pragma unroll
    for (int i = 0; i < 8; i++) acc[i] = (f32x4){0.f, 0.f, 0.f, 0.f};

#pragma unroll
    for (int s = 0; s < 8; ++s) {
        bf16x8 af = *(const bf16x8*)&xt[(s << 9) + lane * 8];
        if (mode == 2) {
#pragma unroll
            for (int nt = 0; nt < 8; nt++) {
                bf16x8 bfrag = *(const bf16x8*)&wf[(s * 8 + nt) * 512];
                acc[nt] = __builtin_amdgcn_mfma_f32_16x16x32_bf16(af, bfrag, acc[nt], 0, 0, 0);
            }
        } else {
#pragma unroll
            for (int nt = 0; nt < 8; nt++) {
                bf16x8 bfrag = *(const bf16x8*)&wf[(s * 8 + nt) * 512];
                acc[nt] = __builtin_amdgcn_mfma_f32_16x16x32_bf16(bfrag, af, acc[nt], 0, 0, 0);
            }
        }
    }

    if (mode == 2) {
        int b_ = (mbase >= SQ) ? 1 : 0;
        int kp0 = mbase - b_ * SQ + wave * 16 + quad * 4;
        int rg = (mbase - b_ * SQ + wave * 16) >> 4;
        int ch = rg >> 3, wp = rg & 3, which = (rg >> 2) & 1;
        float mult[4];
#pragma unroll
        for (int p = 0; p < 4; ++p) {
            int kp = kp0 + p;
            int rr = kp / 56, cc = kp - rr * 56;
            float mr = (((rr >= 1) && (rr <= 3)) || ((rr >= 52) && (rr <= 54))) ? 2.f : 1.f;
            float mc = (((cc >= 1) && (cc <= 3)) || ((cc >= 52) && (cc <= 54))) ? 2.f : 1.f;
            mult[p] = mr * mc;
        }
#pragma unroll
        for (int nt = 0; nt < 8; nt++) {
            int c = nz * 128 + nt * 16 + l16;
            float bvv = bias[c];
            int h_idx = nz * 4 + (nt >> 1);
            int bh2 = b_ * 8 + h_idx;
            float va0 = (acc[nt][0] + bvv) * mult[0];
            float va1 = (acc[nt][1] + bvv) * mult[1];
            float va2 = (acc[nt][2] + bvv) * mult[2];
            float va3 = (acc[nt][3] + bvv) * mult[3];
            uint2 pk = (uint2){pack2bf(va0, va1), pack2bf(va2, va3)};
            size_t off = (size_t)bh2 * 102400 + (size_t)(ch * 4 + wp) * 1024
                       + (size_t)(nt & 1) * 512 + (size_t)(quad * 16 + l16) * 8 + which * 4;
            *(uint2*)&vbf[off] = pk;
        }
    } else {
        u16* outp = (mode == 0) ? qbf : kbf;
        int t = (mbase >> 4) + wave;
        int tt = (mode == 0) ? t : (t + (t >= 196 ? 4 : 0));
#pragma unroll
        for (int nt = 0; nt < 8; nt++) {
            int c0 = nz * 128 + nt * 16 + quad * 4;
            float4 b4 = *(const float4*)&bias[c0];
            float v0 = acc[nt][0] + b4.x * wsc;
            float v1 = acc[nt][1] + b4.y * wsc;
            float v2 = acc[nt][2] + b4.z * wsc;
            float v3 = acc[nt][3] + b4.w * wsc;
            int s_idx = nz * 4 + (nt >> 1);
            int Lrow = ((nt & 1) * 2 + (quad >> 1)) * 16 + l16;
            uint2 pk = (uint2){pack2bf(v0, v1), pack2bf(v2, v3)};
            *(uint2*)&outp[(((size_t)(tt * 8 + s_idx)) << 9) + Lrow * 8 + (quad & 1) * 4] = pk;
        }
    }
}

// ---------------- kernel 2: flash attention (32-query waves, legal 85-reg budget) --
// grid (16 bh, 98 qsub): 1568 blocks x 4 waves x 32 queries = 6272 waves (~6/SIMD).
// launch_bounds(256,6) -> 85 VGPR cap (r12's (256,7)=72 cap caused scratch storm;
// audited demand here ~78). LDS 23.5KB (2 x 8KB K bufs + 7KB counts) -> 6
// blocks/CU, 1536 resident + 32-block tail. K double-buffered wave-private LDS
// (barrier-free); V in registers, depth-1 ping-pong with NAMED sets (no ref-out
// lambdas, all static indexing); counts from LDS for all 25 rounds.
__global__ __launch_bounds__(256, 6) void attn_kernel(const u16* __restrict__ qb,
                                                      const u16* __restrict__ kb,
                                                      const u16* __restrict__ vtb,
                                                      const u16* __restrict__ crow,
                                                      const float* __restrict__ x,
                                                      const float* __restrict__ gammap,
                                                      float* __restrict__ out) {
    __shared__ __align__(16) u16 S[11776];   // K buf0 @0, buf1 @4096; cnt @8192 (3584)

    int tid = threadIdx.x;
    int w = tid >> 6, lane = tid & 63, quad = lane >> 4, l16 = lane & 15;
    int bh = blockIdx.x;
    int b = bh >> 3, h = bh & 7;
    int qy = blockIdx.y;
    int qsub = qy * 32;

    int qtile = b * 196 + qy * 2;
    bf16x8 qf0 = *(const bf16x8*)&qb[(((size_t)(qtile + 0) * 8 + h) << 9) + lane * 8];
    bf16x8 qf1 = *(const bf16x8*)&qb[(((size_t)(qtile + 1) * 8 + h) << 9) + lane * 8];

    const u16* kg = kb + ((size_t)(b * 200) << 12);     // b's K tile base
    const u16* vg = vtb + (size_t)bh * 102400;          // (b,h) V pair-block base

    f32x4 o00 = {0.f,0.f,0.f,0.f}, o01 = {0.f,0.f,0.f,0.f};
    f32x4 o10 = {0.f,0.f,0.f,0.f}, o11 = {0.f,0.f,0.f,0.f};
    f32x4 lv0 = {0.f,0.f,0.f,0.f}, lv1 = {0.f,0.f,0.f,0.f};

    int tA = w, tB = w + 4;
    int kOffA = tA * 512 + lane * 8;
    int kOffB = tB * 512 + lane * 8;
    int cOffA = tA * 16 + quad * 4;
    int cOffB = tB * 16 + quad * 4;
    const u16* vlane = vg + w * 1024 + lane * 8;

#define STAGE_K(r, buf)                                                                   \
    do {                                                                                  \
        u16* base_ = &S[(buf) * 4096];                                                    \
        dma16(kg + (((size_t)(((r) * 8 + tA) * 8 + h)) << 9) + lane * 8,                  \
              base_ + tA * 512, lane);                                                    \
        dma16(kg + (((size_t)(((r) * 8 + tB) * 8 + h)) << 9) + lane * 8,                  \
              base_ + tB * 512, lane);                                                    \
    } while (0)

#define LOAD_V(r, v0, v1)                                                                 \
    do {                                                                                  \
        const u16* vs_ = vlane + (size_t)(r) * 4096;                                      \
        (v0) = *(const uint4*)&vs_[0];                                                    \
        (v1) = *(const uint4*)&vs_[512];                                                  \
    } while (0)

#define BODY(r, buf, v0, v1)                                                              \
    do {                                                                                  \
        const u16* Kl_ = &S[(buf) * 4096];                                                \
        const u16* cnt_ = &S[8192 + (r) * 128];                                           \
        f32x4 z_ = {0.f, 0.f, 0.f, 0.f};                                                  \
        unsigned p00, p01, p02, p03, p10, p11, p12, p13;                                  \
        {                                                                                 \
            bf16x8 kfA_ = *(const bf16x8*)&Kl_[kOffA];                                    \
            __builtin_amdgcn_s_setprio(1);                                                \
            f32x4 e0_ = __builtin_amdgcn_mfma_f32_16x16x32_bf16(kfA_, qf0, z_, 0, 0, 0);  \
            f32x4 e1_ = __builtin_amdgcn_mfma_f32_16x16x32_bf16(kfA_, qf1, z_, 0, 0, 0);  \
            __builtin_amdgcn_s_setprio(0);                                                \
            p00 = cvtpk(exp2_fast(e0_[0]), exp2_fast(e0_[1]));                            \
            p01 = cvtpk(exp2_fast(e0_[2]), exp2_fast(e0_[3]));                            \
            p10 = cvtpk(exp2_fast(e1_[0]), exp2_fast(e1_[1]));                            \
            p11 = cvtpk(exp2_fast(e1_[2]), exp2_fast(e1_[3]));                            \
        }                                                                                 \
        {                                                                                 \
            bf16x8 kfB_ = *(const bf16x8*)&Kl_[kOffB];                                    \
            __builtin_amdgcn_s_setprio(1);                                                \
            f32x4 e0_ = __builtin_amdgcn_mfma_f32_16x16x32_bf16(kfB_, qf0, z_, 0, 0, 0);  \
            f32x4 e1_ = __builtin_amdgcn_mfma_f32_16x16x32_bf16(kfB_, qf1, z_, 0, 0, 0);  \
            __builtin_amdgcn_s_setprio(0);                                                \
            p02 = cvtpk(exp2_fast(e0_[0]), exp2_fast(e0_[1]));                            \
            p03 = cvtpk(exp2_fast(e0_[2]), exp2_fast(e0_[3]));                            \
            p12 = cvtpk(exp2_fast(e1_[0]), exp2_fast(e1_[1]));                            \
            p13 = cvtpk(exp2_fast(e1_[2]), exp2_fast(e1_[3]));                            \
        }                                                                                 \
        uint2 ca_ = *(const uint2*)&cnt_[cOffA];                                          \
        uint2 cb_ = *(const uint2*)&cnt_[cOffB];                                          \
        bf16x8 cf_ = bc8((uint4){ca_.x, ca_.y, cb_.x, cb_.y});                            \
        bf16x8 V0_ = bc8(v0), V1_ = bc8(v1);                                              \
        __builtin_amdgcn_s_setprio(1);                                                    \
        {                                                                                 \
            bf16x8 pa_ = bc8((uint4){p00, p01, p02, p03});                                \
            o00 = __builtin_amdgcn_mfma_f32_16x16x32_bf16(pa_, V0_, o00, 0, 0, 0);        \
            o01 = __builtin_amdgcn_mfma_f32_16x16x32_bf16(pa_, V1_, o01, 0, 0, 0);        \
            lv0 = __builtin_amdgcn_mfma_f32_16x16x32_bf16(pa_, cf_, lv0, 0, 0, 0);        \
        }                                                                                 \
        {                                                                                 \
            bf16x8 pa_ = bc8((uint4){p10, p11, p12, p13});                                \
            o10 = __builtin_amdgcn_mfma_f32_16x16x32_bf16(pa_, V0_, o10, 0, 0, 0);        \
            o11 = __builtin_amdgcn_mfma_f32_16x16x32_bf16(pa_, V1_, o11, 0, 0, 0);        \
            lv1 = __builtin_amdgcn_mfma_f32_16x16x32_bf16(pa_, cf_, lv1, 0, 0, 0);        \
        }                                                                                 \
        __builtin_amdgcn_s_setprio(0);                                                    \
    } while (0)

    // prologue: cnt chunks 0..6 (all 25 rounds) + K(0) + V(0); barrier drains DMAs
    dma16(crow + w * 512 + lane * 8, (char*)&S[8192] + w * 1024, lane);
    if (w < 3)
        dma16(crow + (w + 4) * 512 + lane * 8, (char*)&S[8192] + (w + 4) * 1024, lane);
    STAGE_K(0, 0);
    uint4 va0, va1, vb0, vb1;
    LOAD_V(0, va0, va1);
    __syncthreads();          // compiler drains vmcnt(0): cnt + K(0) + V(0) ready

    for (int j = 0; j < 12; ++j) {
        int r = 2 * j;
        // even round r: consume buf0 + va; prefetch r+1 into buf1 + vb
        STAGE_K(r + 1, 1);
        LOAD_V(r + 1, vb0, vb1);
        asm volatile("s_waitcnt vmcnt(4)" ::: "memory");
        BODY(r, 0, va0, va1);
        // odd round r+1: consume buf1 + vb; prefetch r+2 into buf0 + va
        STAGE_K(r + 2, 0);
        LOAD_V(r + 2, va0, va1);
        asm volatile("s_waitcnt vmcnt(4)" ::: "memory");
        BODY(r + 1, 1, vb0, vb1);
    }
    // round 24 (staged during j=11 odd iter into buf0/va)
    asm volatile("s_waitcnt vmcnt(0)" ::: "memory");
    BODY(24, 0, va0, va1);

    __syncthreads();                 // all waves done; LDS reusable

    // ---- two-stage merge of 4 key-roles via LDS (24 floats/lane payload) ----
    float* mg = (float*)&S[0];
    {
        int slot = ((w & 1) * 64 + lane) * 24;
        if (w >= 2) {
            *(f32x4*)&mg[slot + 0]  = o00;
            *(f32x4*)&mg[slot + 4]  = o01;
            *(f32x4*)&mg[slot + 8]  = o10;
            *(f32x4*)&mg[slot + 12] = o11;
            *(f32x4*)&mg[slot + 16] = lv0;
            *(f32x4*)&mg[slot + 20] = lv1;
        }
        __syncthreads();
        if (w < 2) {
            o00 += *(const f32x4*)&mg[slot + 0];
            o01 += *(const f32x4*)&mg[slot + 4];
            o10 += *(const f32x4*)&mg[slot + 8];
            o11 += *(const f32x4*)&mg[slot + 12];
            lv0 += *(const f32x4*)&mg[slot + 16];
            lv1 += *(const f32x4*)&mg[slot + 20];
        }
        __syncthreads();
    }
    {
        int slot = lane * 24;
        if (w == 1) {
            *(f32x4*)&mg[slot + 0]  = o00;
            *(f32x4*)&mg[slot + 4]  = o01;
            *(f32x4*)&mg[slot + 8]  = o10;
            *(f32x4*)&mg[slot + 12] = o11;
            *(f32x4*)&mg[slot + 16] = lv0;
            *(f32x4*)&mg[slot + 20] = lv1;
        }
        __syncthreads();
        if (w == 0) {
            float gam = gammap[0];
            o00 += *(const f32x4*)&mg[slot + 0];
            o01 += *(const f32x4*)&mg[slot + 4];
            o10 += *(const f32x4*)&mg[slot + 8];
            o11 += *(const f32x4*)&mg[slot + 12];
            lv0 += *(const f32x4*)&mg[slot + 16];
            lv1 += *(const f32x4*)&mg[slot + 20];
#pragma unroll
            for (int r2 = 0; r2 < 4; ++r2) {
                float scl0 = gam / lv0[r2];
                float scl1 = gam / lv1[r2];
                int q0 = qsub + quad * 4 + r2;
                int q1 = q0 + 16;
                size_t base0 = ((size_t)(b * SQ + q0) << 8) + h * 32 + l16;
                size_t base1 = ((size_t)(b * SQ + q1) << 8) + h * 32 + l16;
                out[base0]      = o00[r2] * scl0 + x[base0];
                out[base0 + 16] = o01[r2] * scl0 + x[base0 + 16];
                out[base1]      = o10[r2] * scl1 + x[base1];
                out[base1 + 16] = o11[r2] * scl1 + x[base1 + 16];
            }
        }
    }
#undef STAGE_K
#undef LOAD_V
#undef BODY
}

// ---------------- launcher ----------------
extern "C" void kernel_launch(void* const* d_in, const int* in_sizes, int n_in,
                              void* d_out, int out_size, void* d_ws, size_t ws_size,
                              hipStream_t stream) {
    const float* x     = (const float*)d_in[0];
    const float* Wq    = (const float*)d_in[1];
    const float* bq    = (const float*)d_in[2];
    const float* Wk    = (const float*)d_in[3];
    const float* bk    = (const float*)d_in[4];
    const float* Wv    = (const float*)d_in[5];
    const float* bv    = (const float*)d_in[6];
    const float* gamma = (const float*)d_in[7];
    float* out = (float*)d_out;

    u16* ws   = (u16*)d_ws;
    u16* qbf  = ws + WS_Q;
    u16* kbf  = ws + WS_K;
    u16* vbf  = ws + WS_V;
    u16* wtf  = ws + WS_WT;
    u16* crow = ws + WS_CB;
    u16* xbf  = ws + WS_XB;

    prep_kernel<<<440, 256, 0, stream>>>(x, Wq, Wk, Wv, wtf, kbf, vbf, crow, xbf);
    proj_kernel<<<dim3(98, 3, 2), 256, 0, stream>>>(xbf, wtf, bq, bk, bv, qbf, kbf, vbf);
    attn_kernel<<<dim3(16, 98), 256, 0, stream>>>(qbf, kbf, vbf, crow, x, gamma, out);
}

// Round 14
// 128.502 us; speedup vs baseline: 1.6465x; 1.4410x over previous
//
#include <hip/hip_runtime.h>

// ---------------- types / helpers ----------------
typedef unsigned short u16;
typedef float f32x4 __attribute__((ext_vector_type(4)));
typedef short bf16x8 __attribute__((ext_vector_type(8)));

__device__ __forceinline__ u16 f2bf(float f) {
    unsigned u = __float_as_uint(f);
    u = (u + 0x7FFFu + ((u >> 16) & 1u)) >> 16;
    return (u16)u;
}

#define LOG2E 1.4426950408889634f

#if __has_builtin(__builtin_amdgcn_exp2f)
__device__ __forceinline__ float exp2_fast(float x) { return __builtin_amdgcn_exp2f(x); }
#else
__device__ __forceinline__ float exp2_fast(float x) { return __expf(x * 0.6931471805599453f); }
#endif

__device__ __forceinline__ unsigned pack2bf(float a, float b) {
    unsigned ua = __float_as_uint(a) + 0x8000u;
    unsigned ub = __float_as_uint(b) + 0x8000u;
#if __has_builtin(__builtin_amdgcn_perm)
    return __builtin_amdgcn_perm(ub, ua, 0x07060302u);
#else
    return ((ua >> 16) & 0xFFFFu) | (ub & 0xFFFF0000u);
#endif
}

#if __has_builtin(__builtin_amdgcn_cvt_pk_bf16_f32)
typedef __bf16 bf2_t __attribute__((ext_vector_type(2)));
__device__ __forceinline__ unsigned cvtpk(float a, float b) {
    bf2_t r = __builtin_amdgcn_cvt_pk_bf16_f32(a, b);
    return __builtin_bit_cast(unsigned, r);
}
#else
__device__ __forceinline__ unsigned cvtpk(float a, float b) { return pack2bf(a, b); }
#endif

__device__ __forceinline__ bf16x8 bc8(uint4 u) { return __builtin_bit_cast(bf16x8, u); }

// async 16B/lane global->LDS DMA; lds dst = wave-uniform base + lane*16.
#if __has_builtin(__builtin_amdgcn_global_load_lds)
typedef const __attribute__((address_space(1))) void* as1cv;
typedef __attribute__((address_space(3))) void* as3v;
__device__ __forceinline__ void dma16(const void* g, void* lds_base, int lane) {
    __builtin_amdgcn_global_load_lds((as1cv)g, (as3v)lds_base, 16, 0, 0);
}
#else
__device__ __forceinline__ void dma16(const void* g, void* lds_base, int lane) {
    *(uint4*)((char*)lds_base + lane * 16) = *(const uint4*)g;
}
#endif

// Problem constants. DEDUP: only 3136 unique keys; multiplicity {1,2,4} folded
// into V (pre-scaled) + counts row. All layouts are wave-linear fragment tiles.
// V is PAIR-INTERLEAVED: per (bh, chunk ch, wave w) a 2KB block
// [vh=d-half][reader-lane][16B = {tileA keys 8B, tileB keys 8B}] so attn's PV
// B-fragment is ONE linear ds_read_b128 at base + lane*16.  (HW-verified r10/r11.)
#define BB 2
#define HH 56
#define SQ 3136
#define CROWN 3584

// workspace offsets (u16 units)
#define WS_Q    0         // 392 tiles * 4096
#define WS_K    1605632   // 2 b * 200 tiles * 4096 (196 real + 4 pad)
#define WS_V    3244032   // 16 bh * 25 ch * 4 pair * 1024
#define WS_WT   4882432   // 3*65536 fragment-packed weights
#define WS_CB   5079040   // 3584 u16 bf16 counts
#define WS_XB   5082624   // 392 tiles * 4096 bf16 x

// ---------------- kernel 0: fused prep (weights + x + crow + pad zeros) ------------
__global__ __launch_bounds__(256) void prep_kernel(const float* __restrict__ x,
                                                   const float* __restrict__ Wq,
                                                   const float* __restrict__ Wk,
                                                   const float* __restrict__ Wv,
                                                   u16* __restrict__ wtf,
                                                   u16* __restrict__ kbf,
                                                   u16* __restrict__ vbf,
                                                   u16* __restrict__ crow,
                                                   u16* __restrict__ xbf) {
    __shared__ __align__(16) char SM[17408];
    int tid = threadIdx.x;
    int bid = blockIdx.x;

    if (bid < 48) {
        u16 (*T)[68] = (u16(*)[68])SM;
        int mode = bid >> 4, rem = bid & 15;
        int kx = (rem >> 2) * 64, dx = (rem & 3) * 64;
        const float* W = (mode == 0) ? Wq : ((mode == 1) ? Wk : Wv);
        float sc = (mode == 0) ? LOG2E : 1.0f;
        int r16 = tid >> 4, c4 = (tid & 15) * 4;
#pragma unroll
        for (int p = 0; p < 4; ++p) {
            int kr = p * 16 + r16;
            float4 f = *(const float4*)&W[(size_t)(kx + kr) * 256 + dx + c4];
            T[kr][c4 + 0] = f2bf(f.x * sc);
            T[kr][c4 + 1] = f2bf(f.y * sc);
            T[kr][c4 + 2] = f2bf(f.z * sc);
            T[kr][c4 + 3] = f2bf(f.w * sc);
        }
        __syncthreads();
        int l16 = tid & 15, nt_loc = (tid >> 4) & 3, quad = (tid >> 6) & 3;
#pragma unroll
        for (int s_loc = 0; s_loc < 2; ++s_loc) {
            int k0 = s_loc * 32 + quad * 8;
            int d_loc = nt_loc * 16 + l16;
            u16 tmp[8];
#pragma unroll
            for (int j = 0; j < 8; ++j) tmp[j] = T[k0 + j][d_loc];
            int d = dx + d_loc;
            int nz = d >> 7, ntg = (d >> 4) & 7;
            int s = (kx >> 5) + s_loc;
            int f = (nz * 8 + s) * 8 + ntg;
            int L = quad * 16 + l16;
            *(uint4*)&wtf[(size_t)mode * 65536 + (size_t)f * 512 + (size_t)L * 8] = *(uint4*)tmp;
        }
        uint4 z4 = (uint4){0, 0, 0, 0};
        if (mode == 0 && kx == 0 && dx == 0) {
            // zero K pad tiles 196..199 per b
            for (int i = tid; i < 4096; i += 256) {
                int bb = i >> 11, rem2 = i & 2047;
                int t = 196 + (rem2 >> 9), off = (rem2 & 511) * 8;
                *(uint4*)&kbf[(((size_t)(bb * 200 + t)) << 12) + off] = z4;
            }
        }
        if (mode == 1 && kx == 0 && dx == 0) {
            for (int i = tid; i < CROWN; i += 256) {
                u16 v = 0;
                if (i < SQ) {
                    int rr = i / 56, cc = i - rr * 56;
                    int mr = (((rr >= 1) && (rr <= 3)) || ((rr >= 52) && (rr <= 54))) ? 2 : 1;
                    int mc = (((cc >= 1) && (cc <= 3)) || ((cc >= 52) && (cc <= 54))) ? 2 : 1;
                    int prod = mr * mc;
                    v = (prod == 1) ? (u16)0x3F80 : ((prod == 2) ? (u16)0x4000 : (u16)0x4080);
                }
                crow[i] = v;
            }
        }
        if (mode == 2 && kx == 0 && dx == 0) {
            // zero pair-layout tile-B halves of chunk 24 (pad keys 3136..3199)
            for (int i = tid; i < 8192; i += 256) {
                int bh = i >> 9, rem2 = i & 511;
                int wp = rem2 >> 7, rem3 = rem2 & 127;
                int vh = rem3 >> 6, ln = rem3 & 63;
                size_t off = (size_t)bh * 102400 + (size_t)(96 + wp) * 1024
                           + (size_t)vh * 512 + (size_t)ln * 8 + 4;
                *(uint2*)&vbf[off] = (uint2){0, 0};
            }
        }
    } else {
        float (*T)[256] = (float(*)[256])SM;
        int tile = bid - 48;
        int r = tid >> 4, c0 = (tid & 15) * 16;
        const float* src = x + ((size_t)tile * 16 + r) * 256 + c0;
#pragma unroll
        for (int k = 0; k < 4; ++k)
            *(float4*)&T[r][c0 + k * 4] = *(const float4*)&src[k * 4];
        __syncthreads();
#pragma unroll
        for (int e = 0; e < 2; ++e) {
            int g = tid + e * 256;                  // granule 0..511
            int s = g >> 6, L = g & 63;
            const float* row = &T[L & 15][s * 32 + (L >> 4) * 8];
            uint4 pk = (uint4){pack2bf(row[0], row[1]), pack2bf(row[2], row[3]),
                               pack2bf(row[4], row[5]), pack2bf(row[6], row[7])};
            *(uint4*)&xbf[(size_t)tile * 4096 + (size_t)g * 8] = pk;
        }
    }
}

// ---------------- kernel 1: projections (V store -> pair-interleaved layout) -------
__global__ __launch_bounds__(256, 4) void proj_kernel(const u16* __restrict__ xbf,
                                                      const u16* __restrict__ wtf,
                                                      const float* __restrict__ bq,
                                                      const float* __restrict__ bk,
                                                      const float* __restrict__ bv,
                                                      u16* __restrict__ qbf,
                                                      u16* __restrict__ kbf,
                                                      u16* __restrict__ vbf) {
    int mode = blockIdx.y, nz = blockIdx.z;
    int mbase = blockIdx.x * 64;
    int tid = threadIdx.x;
    int wave = tid >> 6, lane = tid & 63, quad = (tid >> 4) & 3, l16 = tid & 15;
    const float* bias = (mode == 0) ? bq : ((mode == 1) ? bk : bv);
    float wsc = (mode == 0) ? LOG2E : 1.0f;
    const u16* wf = wtf + (size_t)mode * 65536 + (size_t)nz * 32768 + (size_t)lane * 8;
    const u16* xt = xbf + (((size_t)(mbase >> 4) + wave) << 12);   // tile base (*4096)

    f32x4 acc[8];
#pragma unroll
    for (int i = 0; i < 8; i++) acc[i] = (f32x4){0.f, 0.f, 0.f, 0.f};

#pragma unroll
    for (int s = 0; s < 8; ++s) {
        bf16x8 af = *(const bf16x8*)&xt[(s << 9) + lane * 8];
        if (mode == 2) {
#pragma unroll
            for (int nt = 0; nt < 8; nt++) {
                bf16x8 bfrag = *(const bf16x8*)&wf[(s * 8 + nt) * 512];
                acc[nt] = __builtin_amdgcn_mfma_f32_16x16x32_bf16(af, bfrag, acc[nt], 0, 0, 0);
            }
        } else {
#pragma unroll
            for (int nt = 0; nt < 8; nt++) {
                bf16x8 bfrag = *(const bf16x8*)&wf[(s * 8 + nt) * 512];
                acc[nt] = __builtin_amdgcn_mfma_f32_16x16x32_bf16(bfrag, af, acc[nt], 0, 0, 0);
            }
        }
    }

    if (mode == 2) {
        int b_ = (mbase >= SQ) ? 1 : 0;
        int kp0 = mbase - b_ * SQ + wave * 16 + quad * 4;
        int rg = (mbase - b_ * SQ + wave * 16) >> 4;
        int ch = rg >> 3, wp = rg & 3, which = (rg >> 2) & 1;
        float mult[4];
#pragma unroll
        for (int p = 0; p < 4; ++p) {
            int kp = kp0 + p;
            int rr = kp / 56, cc = kp - rr * 56;
            float mr = (((rr >= 1) && (rr <= 3)) || ((rr >= 52) && (rr <= 54))) ? 2.f : 1.f;
            float mc = (((cc >= 1) && (cc <= 3)) || ((cc >= 52) && (cc <= 54))) ? 2.f : 1.f;
            mult[p] = mr * mc;
        }
#pragma unroll
        for (int nt = 0; nt < 8; nt++) {
            int c = nz * 128 + nt * 16 + l16;
            float bvv = bias[c];
            int h_idx = nz * 4 + (nt >> 1);
            int bh2 = b_ * 8 + h_idx;
            float va0 = (acc[nt][0] + bvv) * mult[0];
            float va1 = (acc[nt][1] + bvv) * mult[1];
            float va2 = (acc[nt][2] + bvv) * mult[2];
            float va3 = (acc[nt][3] + bvv) * mult[3];
            uint2 pk = (uint2){pack2bf(va0, va1), pack2bf(va2, va3)};
            size_t off = (size_t)bh2 * 102400 + (size_t)(ch * 4 + wp) * 1024
                       + (size_t)(nt & 1) * 512 + (size_t)(quad * 16 + l16) * 8 + which * 4;
            *(uint2*)&vbf[off] = pk;
        }
    } else {
        u16* outp = (mode == 0) ? qbf : kbf;
        int t = (mbase >> 4) + wave;
        int tt = (mode == 0) ? t : (t + (t >= 196 ? 4 : 0));
#pragma unroll
        for (int nt = 0; nt < 8; nt++) {
            int c0 = nz * 128 + nt * 16 + quad * 4;
            float4 b4 = *(const float4*)&bias[c0];
            float v0 = acc[nt][0] + b4.x * wsc;
            float v1 = acc[nt][1] + b4.y * wsc;
            float v2 = acc[nt][2] + b4.z * wsc;
            float v3 = acc[nt][3] + b4.w * wsc;
            int s_idx = nz * 4 + (nt >> 1);
            int Lrow = ((nt & 1) * 2 + (quad >> 1)) * 16 + l16;
            uint2 pk = (uint2){pack2bf(v0, v1), pack2bf(v2, v3)};
            *(uint2*)&outp[(((size_t)(tt * 8 + s_idx)) << 9) + Lrow * 8 + (quad & 1) * 4] = pk;
        }
    }
}

// ---------------- kernel 2: flash attention (round-11 best: free-run + pair-V) -----
// grid (16 bh, 49 qsub), 256 thr = 4 free-running waves (wave-private LDS, no
// loop barriers). Depth-1 prefetch, counted vmcnt(4). V reads are single linear
// ds_read_b128 per d-half (pair-interleaved layout). T5 setprio on MFMA clusters.
__global__ __launch_bounds__(256, 4) void attn_kernel(const u16* __restrict__ qb,
                                                      const u16* __restrict__ kb,
                                                      const u16* __restrict__ vtb,
                                                      const u16* __restrict__ crow,
                                                      const float* __restrict__ x,
                                                      const float* __restrict__ gammap,
                                                      float* __restrict__ out) {
    __shared__ __align__(16) u16 S[19968];   // buf b at b*8192: K 8 tiles +0, V 4 pairs +4096; cnt @16384

    int tid = threadIdx.x;
    int w = tid >> 6, lane = tid & 63, quad = lane >> 4, l16 = lane & 15;
    int bh = blockIdx.x;
    int b = bh >> 3, h = bh & 7;
    int qsub = blockIdx.y * 64;

    int qtile = b * 196 + blockIdx.y * 4;
    bf16x8 qf[4];
#pragma unroll
    for (int i = 0; i < 4; ++i)
        qf[i] = *(const bf16x8*)&qb[(((size_t)(qtile + i) * 8 + h) << 9) + lane * 8];

    const u16* kg = kb + ((size_t)(b * 200) << 12);     // b's K tile base
    const u16* vg = vtb + (size_t)bh * 102400;          // (b,h) V pair-block base

    f32x4 o[4][2], lv[4];
#pragma unroll
    for (int i = 0; i < 4; ++i) {
        o[i][0] = (f32x4){0.f, 0.f, 0.f, 0.f};
        o[i][1] = (f32x4){0.f, 0.f, 0.f, 0.f};
        lv[i]   = (f32x4){0.f, 0.f, 0.f, 0.f};
    }

    int tA = w, tB = w + 4;
    // wave w stages K tiles {w, w+4} + its own V pair-block: 4 x 1KB linear DMAs
    auto stage = [&](int r_ch, int buf) {
        u16* base = &S[buf * 8192];
        int rgA = r_ch * 8 + tA, rgB = r_ch * 8 + tB;
        dma16(kg + (((size_t)rgA * 8 + h) << 9) + lane * 8, base + tA * 512, lane);
        dma16(kg + (((size_t)rgB * 8 + h) << 9) + lane * 8, base + tB * 512, lane);
        const u16* vsrc = vg + (size_t)r_ch * 4096 + w * 1024;
        dma16(vsrc + lane * 8, base + 4096 + w * 1024, lane);
        dma16(vsrc + 512 + lane * 8, base + 4096 + w * 1024 + 512, lane);
    };

    int kOffA = tA * 512 + lane * 8;
    int kOffB = tB * 512 + lane * 8;
    int vOff  = 4096 + w * 1024 + lane * 8;
    int cOffA = tA * 16 + quad * 4;
    int cOffB = tB * 16 + quad * 4;

    auto round_body = [&](int r, int bR) {
        const u16* Kl = &S[bR * 8192];
        const u16* cnt = &S[16384] + r * 128;
        f32x4 z = (f32x4){0.f, 0.f, 0.f, 0.f};
        unsigned paw[4][4];

        {
            bf16x8 kfA = *(const bf16x8*)&Kl[kOffA];
            f32x4 eA[4];
            __builtin_amdgcn_s_setprio(1);
#pragma unroll
            for (int i = 0; i < 4; ++i)
                eA[i] = __builtin_amdgcn_mfma_f32_16x16x32_bf16(kfA, qf[i], z, 0, 0, 0);
            __builtin_amdgcn_s_setprio(0);
#pragma unroll
            for (int i = 0; i < 4; ++i) {
                paw[i][0] = cvtpk(exp2_fast(eA[i][0]), exp2_fast(eA[i][1]));
                paw[i][1] = cvtpk(exp2_fast(eA[i][2]), exp2_fast(eA[i][3]));
            }
        }
        {
            bf16x8 kfB = *(const bf16x8*)&Kl[kOffB];
            f32x4 eB[4];
            __builtin_amdgcn_s_setprio(1);
#pragma unroll
            for (int i = 0; i < 4; ++i)
                eB[i] = __builtin_amdgcn_mfma_f32_16x16x32_bf16(kfB, qf[i], z, 0, 0, 0);
            __builtin_amdgcn_s_setprio(0);
#pragma unroll
            for (int i = 0; i < 4; ++i) {
                paw[i][2] = cvtpk(exp2_fast(eB[i][0]), exp2_fast(eB[i][1]));
                paw[i][3] = cvtpk(exp2_fast(eB[i][2]), exp2_fast(eB[i][3]));
            }
        }
        uint2 ca = *(const uint2*)&cnt[cOffA];
        uint2 cc = *(const uint2*)&cnt[cOffB];
        bf16x8 cf = bc8((uint4){ca.x, ca.y, cc.x, cc.y});
        bf16x8 V0 = *(const bf16x8*)&Kl[vOff];          // pair layout: one b128 per d-half
        bf16x8 V1 = *(const bf16x8*)&Kl[vOff + 512];

        __builtin_amdgcn_s_setprio(1);
#pragma unroll
        for (int i = 0; i < 4; ++i) {
            bf16x8 pa = bc8((uint4){paw[i][0], paw[i][1], paw[i][2], paw[i][3]});
            o[i][0] = __builtin_amdgcn_mfma_f32_16x16x32_bf16(pa, V0, o[i][0], 0, 0, 0);
            o[i][1] = __builtin_amdgcn_mfma_f32_16x16x32_bf16(pa, V1, o[i][1], 0, 0, 0);
            lv[i]   = __builtin_amdgcn_mfma_f32_16x16x32_bf16(pa, cf, lv[i], 0, 0, 0);
        }
        __builtin_amdgcn_s_setprio(0);
    };

    // prologue: counts (wave w stages chunks w and w+4<7) + stage(0); ONE barrier
    {
        dma16(crow + w * 512 + lane * 8, (char*)&S[16384] + w * 1024, lane);
        if (w + 4 < 7)
            dma16(crow + (w + 4) * 512 + lane * 8, (char*)&S[16384] + (w + 4) * 1024, lane);
    }
    stage(0, 0);
    __syncthreads();                 // drains all DMA (cnt + buf0) for all waves

    for (int r = 0; r < 25; ++r) {
        if (r + 1 < 25) {
            stage(r + 1, (r + 1) & 1);                         // 4 DMAs, flies under body(r)
            asm volatile("s_waitcnt vmcnt(4)" ::: "memory");   // stage(r) complete
        } else {
            asm volatile("s_waitcnt vmcnt(0)" ::: "memory");
        }
        round_body(r, r & 1);
    }
    __syncthreads();                 // all waves done; LDS reusable

    // ---- two-stage merge of 4 key-roles via LDS ----
    float* mg = (float*)&S[0];
    {
        int slot = ((w & 1) * 64 + lane) * 48;
        if (w >= 2) {
#pragma unroll
            for (int i = 0; i < 4; ++i) {
                *(f32x4*)&mg[slot + i * 8]      = o[i][0];
                *(f32x4*)&mg[slot + i * 8 + 4]  = o[i][1];
                *(f32x4*)&mg[slot + 32 + i * 4] = lv[i];
            }
        }
        __syncthreads();
        if (w < 2) {
#pragma unroll
            for (int i = 0; i < 4; ++i) {
                o[i][0] += *(const f32x4*)&mg[slot + i * 8];
                o[i][1] += *(const f32x4*)&mg[slot + i * 8 + 4];
                lv[i]   += *(const f32x4*)&mg[slot + 32 + i * 4];
            }
        }
        __syncthreads();
    }
    {
        int slot = lane * 48;
        if (w == 1) {
#pragma unroll
            for (int i = 0; i < 4; ++i) {
                *(f32x4*)&mg[slot + i * 8]      = o[i][0];
                *(f32x4*)&mg[slot + i * 8 + 4]  = o[i][1];
                *(f32x4*)&mg[slot + 32 + i * 4] = lv[i];
            }
        }
        __syncthreads();
        if (w == 0) {
            float gam = gammap[0];
#pragma unroll
            for (int i = 0; i < 4; ++i) {
                o[i][0] += *(const f32x4*)&mg[slot + i * 8];
                o[i][1] += *(const f32x4*)&mg[slot + i * 8 + 4];
                lv[i]   += *(const f32x4*)&mg[slot + 32 + i * 4];
#pragma unroll
                for (int r2 = 0; r2 < 4; ++r2) {
                    float scl = gam / lv[i][r2];
                    int q = qsub + i * 16 + quad * 4 + r2;
                    size_t base = ((size_t)(b * SQ + q) << 8) + h * 32 + l16;
                    out[base]      = o[i][0][r2] * scl + x[base];
                    out[base + 16] = o[i][1][r2] * scl + x[base + 16];
                }
            }
        }
    }
}

// ---------------- launcher ----------------
extern "C" void kernel_launch(void* const* d_in, const int* in_sizes, int n_in,
                              void* d_out, int out_size, void* d_ws, size_t ws_size,
                              hipStream_t stream) {
    const float* x     = (const float*)d_in[0];
    const float* Wq    = (const float*)d_in[1];
    const float* bq    = (const float*)d_in[2];
    const float* Wk    = (const float*)d_in[3];
    const float* bk    = (const float*)d_in[4];
    const float* Wv    = (const float*)d_in[5];
    const float* bv    = (const float*)d_in[6];
    const float* gamma = (const float*)d_in[7];
    float* out = (float*)d_out;

    u16* ws   = (u16*)d_ws;
    u16* qbf  = ws + WS_Q;
    u16* kbf  = ws + WS_K;
    u16* vbf  = ws + WS_V;
    u16* wtf  = ws + WS_WT;
    u16* crow = ws + WS_CB;
    u16* xbf  = ws + WS_XB;

    prep_kernel<<<440, 256, 0, stream>>>(x, Wq, Wk, Wv, wtf, kbf, vbf, crow, xbf);
    proj_kernel<<<dim3(98, 3, 2), 256, 0, stream>>>(xbf, wtf, bq, bk, bv, qbf, kbf, vbf);
    attn_kernel<<<dim3(16, 49), 256, 0, stream>>>(qbf, kbf, vbf, crow, x, gamma, out);
}